// Round 9
// baseline (140.092 us; speedup 1.0000x reference)
//
#include <hip/hip_runtime.h>

#define IN_F 1024
#define OUT_F 1024
#define NT 1024
#define RANK 32
#define M_TOT 8192   // 4*2048 query rows
#define N2T 2048     // 2*NT combined tokens

typedef __attribute__((ext_vector_type(8))) short short8;
typedef __attribute__((ext_vector_type(4))) float f32x4;
typedef __attribute__((ext_vector_type(8))) unsigned short ushort8;

__device__ __forceinline__ float geluf(float x) {
  return 0.5f * x * (1.0f + erff(x * 0.7071067811865476f));
}
__device__ __forceinline__ unsigned short f2bf(float f) {
  unsigned x = __float_as_uint(f);
  return (unsigned short)((x + 0x7fffu + ((x >> 16) & 1u)) >> 16);
}
__device__ __forceinline__ float bf2f(unsigned short u) {
  return __uint_as_float(((unsigned)u) << 16);
}

// ---- prep kernels ----------------------------------------------------------

// tmp = T @ D  ([1024][32]); 4 rows per block (grid 512), rows staged
// TRANSPOSED in LDS so the k-loop is 1 ds_read_b128 + 1 D-load + 4 indep FMAs.
// Cuts D L2-traffic 256MB -> 64MB and breaks the FMA dep chain. Also zeroes rowsq.
__global__ __launch_bounds__(256) void down_proj_kernel(
    const float* __restrict__ kt, const float* __restrict__ kd,
    const float* __restrict__ vt, const float* __restrict__ vd,
    float* __restrict__ tmpK, float* __restrict__ tmpV,
    float* __restrict__ rowsq) {
  __shared__ float rowbufT[IN_F][4];   // [k][row] 16 KB
  __shared__ float part[8][32][4];     // [kchunk][c][row] 4 KB
  const int tid = threadIdx.x;
  if (blockIdx.x < 32) rowsq[blockIdx.x * 256 + tid] = 0.f;
  const int mat = blockIdx.x >> 8;          // 256 blocks per matrix
  const int r0 = (blockIdx.x & 255) * 4;
  const float* T = mat ? vt : kt;
  const float* D = mat ? vd : kd;
  float* OUT = mat ? tmpV : tmpK;
  // stage 4 rows transposed: wave w stages row w
  {
    const int rr = tid >> 6;
    const int lane = tid & 63;
#pragma unroll
    for (int i = 0; i < 4; ++i) {
      int col = lane * 4 + i * 256;
      f32x4 v = *(const f32x4*)(T + (size_t)(r0 + rr) * IN_F + col);
#pragma unroll
      for (int j = 0; j < 4; ++j) rowbufT[col + j][rr] = v[j];
    }
  }
  __syncthreads();
  const int c = tid & 31;
  const int kc = tid >> 5;  // 8 chunks of 128 k
  float s0 = 0.f, s1 = 0.f, s2 = 0.f, s3 = 0.f;
#pragma unroll 4
  for (int k = kc * 128; k < kc * 128 + 128; ++k) {
    float d = D[k * RANK + c];
    f32x4 r = *(const f32x4*)(&rowbufT[k][0]);
    s0 += r[0] * d; s1 += r[1] * d; s2 += r[2] * d; s3 += r[3] * d;
  }
  *(f32x4*)(&part[kc][c][0]) = (f32x4){s0, s1, s2, s3};
  __syncthreads();
  if (tid < 128) {
    const int rr = tid >> 5;
    const int cc = tid & 31;
    float a = 0.f;
#pragma unroll
    for (int i = 0; i < 8; ++i) a += part[i][cc][rr];
    OUT[(size_t)(r0 + rr) * RANK + cc] = a;
  }
}

// One merged prep kernel:
//   [0,4096)    xcast x -> xb
//   [4096,4608) cast key_tokens -> Kb[0:NT]
//   [4608,5120) upK: Kb[NT+t][d] = bf16(gelu(tmpK @ key_up))
//   [5120,5376) vcopy: VbT[e][t<NT] = transpose(value_tokens)
//   [5376,5888) upV: VbT[e][NT+t] = bf16(gelu(tmpV @ value_up))
__global__ __launch_bounds__(256) void prep_all_kernel(
    const float* __restrict__ x, const float* __restrict__ key_tokens,
    const float* __restrict__ value_tokens, const float* __restrict__ key_up,
    const float* __restrict__ value_up, const float* __restrict__ tmpK,
    const float* __restrict__ tmpV, unsigned short* __restrict__ xb,
    unsigned short* __restrict__ Kb, unsigned short* __restrict__ VbT) {
  __shared__ float smem[64 * 65 + 32 * 64];
  const int tid = threadIdx.x;
  const int bid = blockIdx.x;
  if (bid < 4608) {
    const float* src = (bid < 4096) ? x : key_tokens;
    unsigned short* dst = (bid < 4096) ? xb : Kb;
    int b = (bid < 4096) ? bid : (bid - 4096);
    int base = (b * 256 + tid) * 8;
    f32x4 a = *(const f32x4*)(src + base);
    f32x4 c = *(const f32x4*)(src + base + 4);
    ushort8 o;
    o[0] = f2bf(a[0]); o[1] = f2bf(a[1]); o[2] = f2bf(a[2]); o[3] = f2bf(a[3]);
    o[4] = f2bf(c[0]); o[5] = f2bf(c[1]); o[6] = f2bf(c[2]); o[7] = f2bf(c[3]);
    *(ushort8*)(dst + base) = o;
    return;
  }
  if (bid < 5120) {
    const int b = bid - 4608;
    float* ldsT = smem;               // [32][33]
    float* ldsU = smem + 64 * 65;     // [32][64]
    const int t0 = (b >> 4) * 32;
    const int d0 = (b & 15) * 64;
    {
      int row = tid >> 3, col = (tid & 7) * 4;
      f32x4 v = *(const f32x4*)(tmpK + (size_t)(t0 + row) * RANK + col);
#pragma unroll
      for (int j = 0; j < 4; ++j) ldsT[row * 33 + col + j] = v[j];
    }
#pragma unroll
    for (int s = 0; s < 2; ++s) {
      int idx = s * 1024 + tid * 4;
      int r = idx >> 6, cc = idx & 63;
      *(f32x4*)(ldsU + idx) = *(const f32x4*)(key_up + (size_t)r * IN_F + d0 + cc);
    }
    __syncthreads();
    const int lane = tid & 63;
    const int w = tid >> 6;
    float acc[8];
#pragma unroll
    for (int i = 0; i < 8; ++i) acc[i] = 0.f;
#pragma unroll
    for (int r = 0; r < RANK; ++r) {
      float wv = ldsU[r * 64 + lane];
#pragma unroll
      for (int i = 0; i < 8; ++i) acc[i] += ldsT[(w * 8 + i) * 33 + r] * wv;
    }
#pragma unroll
    for (int i = 0; i < 8; ++i)
      Kb[(size_t)(NT + t0 + w * 8 + i) * IN_F + d0 + lane] = f2bf(geluf(acc[i]));
    return;
  }
  if (bid < 5376) {
    const int b = bid - 5120;
    float (*tile)[65] = (float (*)[65])smem;
    int t0 = (b & 15) * 64, e0 = (b >> 4) * 64;
#pragma unroll 1
    for (int it = 0; it < 16; ++it) {
      int tt = it * 4 + (tid >> 6);
      int ee = tid & 63;
      tile[tt][ee] = value_tokens[(size_t)(t0 + tt) * OUT_F + e0 + ee];
    }
    __syncthreads();
#pragma unroll 1
    for (int it = 0; it < 16; ++it) {
      int ee = it * 4 + (tid >> 6);
      int tt = tid & 63;
      VbT[(size_t)(e0 + ee) * N2T + t0 + tt] = f2bf(tile[tt][ee]);
    }
    return;
  }
  {
    const int b = bid - 5376;
    float* ldsT = smem;               // [64][33]
    float* ldsU = smem + 64 * 65;     // [32][32]
    const int t0 = (b >> 5) * 64;
    const int e0 = (b & 31) * 32;
#pragma unroll
    for (int s = 0; s < 2; ++s) {
      int idx = s * 1024 + tid * 4;
      int row = idx >> 5, col = idx & 31;
      f32x4 v = *(const f32x4*)(tmpV + (size_t)(t0 + row) * RANK + col);
#pragma unroll
      for (int j = 0; j < 4; ++j) ldsT[row * 33 + col + j] = v[j];
    }
    {
      int r = tid >> 3, col = (tid & 7) * 4;
      *(f32x4*)(ldsU + r * 32 + col) = *(const f32x4*)(value_up + (size_t)r * OUT_F + e0 + col);
    }
    __syncthreads();
    const int lane = tid & 63;
    const int w = tid >> 6;
    float acc[8];
#pragma unroll
    for (int i = 0; i < 8; ++i) acc[i] = 0.f;
#pragma unroll
    for (int r = 0; r < RANK; ++r) {
      float uv = ldsT[lane * 33 + r];
#pragma unroll
      for (int i = 0; i < 8; ++i) acc[i] += uv * ldsU[r * 32 + w * 8 + i];
    }
#pragma unroll
    for (int i = 0; i < 8; ++i)
      VbT[(size_t)(e0 + w * 8 + i) * N2T + NT + t0 + lane] = f2bf(geluf(acc[i]));
  }
}

// standalone scale+gelu pass: W = bf16(gelu(S * sqrt(2048/rowsq))) in place
__global__ void gelu_kernel(unsigned short* __restrict__ S, const float* __restrict__ rowsq) {
  int base = (blockIdx.x * blockDim.x + threadIdx.x) * 8;
  int row = base >> 11;
  float scale = sqrtf(2048.0f / rowsq[row]);
  ushort8 v = *(const ushort8*)(S + base);
  ushort8 o;
#pragma unroll
  for (int i = 0; i < 8; ++i) o[i] = f2bf(geluf(bf2f(v[i]) * scale));
  *(ushort8*)(S + base) = o;
}

// ---- 2-phase GEMM (R4-verified): C[M,N] = A[M,K]*B[N,K]^T, BM=256, BK=64 ---
// Phase A reads A0,B0,B1 -> 32 MFMA; phase B reads A1 -> 32 MFMA.
// Stage slots (>=1 barrier after target region's last read):
//   phA: A1(t+1) -> other buf; phB: A0,B0,B1(t+2) -> current buf.
// Boundary vmcnt(2+2*LB): drains through t.phA's A1(t+1) -> t+1 fully staged.
#define BARRB __builtin_amdgcn_s_barrier()

template <int BN, int KDIM, int NDIM, int DO_SIM>
__global__ __launch_bounds__(512, 2) void gemm2p_kernel(
    const unsigned short* __restrict__ A, const unsigned short* __restrict__ Bm,
    void* __restrict__ Cout, float* __restrict__ rowsq) {
  constexpr int NFRAG = BN / 64;
  constexpr int NH = NFRAG / 2;
  constexpr int LB = BN / 128;
  constexpr int ABUFE = 16384;
  constexpr int BBUFE = BN * 64;
  constexpr int nTN = NDIM / BN;
  constexpr int nkt = KDIM / 64;
  __shared__ unsigned short lds[2 * ABUFE + 2 * BBUFE];

  const int tid = threadIdx.x;
  const int l = tid & 63;
  const int wid = tid >> 6;
  const int wr = wid >> 2;
  const int wc = wid & 3;

  const int nwg = gridDim.x;
  const int cpx = nwg >> 3;
  const int wg = (blockIdx.x & 7) * cpx + (blockIdx.x >> 3);
  const int bx = wg % nTN;
  const int by = wg / nTN;
  const int rowBase = by * 256;
  const int colBase = bx * BN;

  const unsigned short* aSrc[2]; int aLds[2];
#pragma unroll
  for (int j = 0; j < 2; ++j) {
    int slot = j * 512 + tid;
    int rin = slot >> 3;
    int cs = (slot & 7) ^ (rin & 7);
    aSrc[j] = A + (size_t)(rowBase + rin) * KDIM + cs * 8;
    aLds[j] = slot * 8;
  }
  const unsigned short* bSrc[LB]; int bLds[LB];
#pragma unroll
  for (int j = 0; j < LB; ++j) {
    int slot = j * 512 + tid;
    int rin = slot >> 3;
    int cs = (slot & 7) ^ (rin & 7);
    bSrc[j] = Bm + (size_t)(colBase + rin) * KDIM + cs * 8;
    bLds[j] = slot * 8;
  }

#define STAGE_A(u, b, kt) { _Pragma("unroll") for (int j = 0; j < 2; ++j) \
    __builtin_amdgcn_global_load_lds( \
      (const __attribute__((address_space(1))) void*)(aSrc[j] + (size_t)(u) * 128 * KDIM + (kt) * 64), \
      (__attribute__((address_space(3))) void*)(lds + (b) * ABUFE + (u) * 8192 + aLds[j]), 16, 0, 0); }
#define STAGE_B(u, b, kt) { _Pragma("unroll") for (int j = 0; j < LB; ++j) \
    __builtin_amdgcn_global_load_lds( \
      (const __attribute__((address_space(1))) void*)(bSrc[j] + (size_t)(u) * (BN / 2) * KDIM + (kt) * 64), \
      (__attribute__((address_space(3))) void*)(lds + 2 * ABUFE + (b) * BBUFE + (u) * (BBUFE / 2) + bLds[j]), 16, 0, 0); }

  const int kb0 = (l >> 4) * 16;
  const int sw = (l & 7) << 4;
  const int lr = l & 15;

  f32x4 acc[8][NFRAG];
#pragma unroll
  for (int m = 0; m < 8; ++m)
#pragma unroll
    for (int n = 0; n < NFRAG; ++n) acc[m][n] = (f32x4){0.f, 0.f, 0.f, 0.f};

  short8 a[4][2], b0[NH][2], b1[NH][2];

#define LDA(mh, bb_) { _Pragma("unroll") for (int i = 0; i < 4; ++i) { \
    int row = ((mh) * 4 + i) * 32 + wr * 16 + lr; \
    const char* pp = (const char*)lds + (bb_) * 32768 + row * 128; \
    a[i][0] = *(const short8*)(pp + ((0 + kb0) ^ sw)); \
    a[i][1] = *(const short8*)(pp + ((64 + kb0) ^ sw)); } }
#define LDB(dst, nh, bb_) { _Pragma("unroll") for (int i = 0; i < NH; ++i) { \
    int row = ((nh) * NH + i) * 64 + wc * 16 + lr; \
    const char* pp = (const char*)lds + 2 * ABUFE * 2 + (bb_) * BBUFE * 2 + row * 128; \
    dst[i][0] = *(const short8*)(pp + ((0 + kb0) ^ sw)); \
    dst[i][1] = *(const short8*)(pp + ((64 + kb0) ^ sw)); } }
#define DO_MFMA(mh, nh, bb) { _Pragma("unroll") for (int kk = 0; kk < 2; ++kk) \
    _Pragma("unroll") for (int i = 0; i < 4; ++i) \
    _Pragma("unroll") for (int nn = 0; nn < NH; ++nn) \
      acc[(mh) * 4 + i][(nh) * NH + nn] = __builtin_amdgcn_mfma_f32_16x16x32_bf16( \
          a[i][kk], bb[nn][kk], acc[(mh) * 4 + i][(nh) * NH + nn], 0, 0, 0); }

  STAGE_A(0, 0, 0); STAGE_A(1, 0, 0); STAGE_B(0, 0, 0); STAGE_B(1, 0, 0);
  STAGE_A(0, 1, 1); STAGE_B(0, 1, 1); STAGE_B(1, 1, 1);
  if constexpr (LB == 2) { asm volatile("s_waitcnt vmcnt(6)" ::: "memory"); }
  else                   { asm volatile("s_waitcnt vmcnt(4)" ::: "memory"); }
  BARRB;

  for (int t = 0; t < nkt; ++t) {
    const int buf = t & 1;
    LDA(0, buf); LDB(b0, 0, buf); LDB(b1, 1, buf);
    if (t + 1 < nkt) STAGE_A(1, buf ^ 1, t + 1);
    BARRB;
    __builtin_amdgcn_s_setprio(1);
    DO_MFMA(0, 0, b0); DO_MFMA(0, 1, b1);
    __builtin_amdgcn_s_setprio(0);
    BARRB;
    LDA(1, buf);
    if (t + 2 < nkt) { STAGE_A(0, buf, t + 2); STAGE_B(0, buf, t + 2); STAGE_B(1, buf, t + 2); }
    BARRB;
    __builtin_amdgcn_s_setprio(1);
    DO_MFMA(1, 1, b1); DO_MFMA(1, 0, b0);
    __builtin_amdgcn_s_setprio(0);
    if constexpr (LB == 2) { asm volatile("s_waitcnt vmcnt(6)" ::: "memory"); }
    else                   { asm volatile("s_waitcnt vmcnt(4)" ::: "memory"); }
    BARRB;
  }

  // epilogue: C/D layout col=lane&15, row=(lane>>4)*4+reg
  const int cq = l >> 4;
  const int cc = l & 15;
  if constexpr (DO_SIM) {
    unsigned short* Sb = (unsigned short*)Cout;
#pragma unroll
    for (int m = 0; m < 8; ++m) {
#pragma unroll
      for (int j = 0; j < 4; ++j) {
        int gr = rowBase + m * 32 + wr * 16 + cq * 4 + j;
        float ss = 0.f;
#pragma unroll
        for (int n = 0; n < NFRAG; ++n) {
          float v = acc[m][n][j];
          ss += v * v;
          Sb[(size_t)gr * NDIM + colBase + n * 64 + wc * 16 + cc] = f2bf(v);
        }
        ss += __shfl_xor(ss, 1, 64);
        ss += __shfl_xor(ss, 2, 64);
        ss += __shfl_xor(ss, 4, 64);
        ss += __shfl_xor(ss, 8, 64);
        if (cc == 0) atomicAdd(&rowsq[gr], ss);
      }
    }
  } else {
    float* Co = (float*)Cout;
#pragma unroll
    for (int m = 0; m < 8; ++m) {
#pragma unroll
      for (int j = 0; j < 4; ++j) {
        int gr = rowBase + m * 32 + wr * 16 + cq * 4 + j;
#pragma unroll
        for (int n = 0; n < NFRAG; ++n)
          Co[(size_t)gr * NDIM + colBase + n * 64 + wc * 16 + cc] = acc[m][n][j];
      }
    }
  }
#undef STAGE_A
#undef STAGE_B
#undef LDA
#undef LDB
#undef DO_MFMA
}

// ---- launch ----------------------------------------------------------------

extern "C" void kernel_launch(void* const* d_in, const int* in_sizes, int n_in,
                              void* d_out, int out_size, void* d_ws, size_t ws_size,
                              hipStream_t stream) {
  (void)in_sizes; (void)n_in; (void)out_size; (void)ws_size;
  const float* x            = (const float*)d_in[0];
  const float* key_tokens   = (const float*)d_in[1];
  const float* value_tokens = (const float*)d_in[2];
  const float* key_down     = (const float*)d_in[3];
  const float* key_up       = (const float*)d_in[4];
  const float* value_down   = (const float*)d_in[5];
  const float* value_up     = (const float*)d_in[6];

  char* ws = (char*)d_ws;
  unsigned short* xb  = (unsigned short*)(ws);              // 16 MB  [8192][1024]
  unsigned short* Kb  = (unsigned short*)(ws + 16777216);   // 4 MB   [2048][1024]
  unsigned short* VbT = (unsigned short*)(ws + 20971520);   // 4 MB   [1024][2048]
  unsigned short* S   = (unsigned short*)(ws + 25165824);   // 32 MB  [8192][2048]
  float* tmpK  = (float*)(ws + 58720256);                   // 128 KB
  float* tmpV  = (float*)(ws + 58851328);                   // 128 KB
  float* rowsq = (float*)(ws + 58982400);                   // 32 KB

  down_proj_kernel<<<512, 256, 0, stream>>>(key_tokens, key_down, value_tokens, value_down,
                                            tmpK, tmpV, rowsq);
  prep_all_kernel<<<5888, 256, 0, stream>>>(x, key_tokens, value_tokens, key_up, value_up,
                                            tmpK, tmpV, xb, Kb, VbT);
  // GEMM1: S = xb @ Kb^T  [8192,2048], K=1024 (+ rowsq)
  gemm2p_kernel<256, IN_F, N2T, 1><<<256, 512, 0, stream>>>(xb, Kb, (void*)S, rowsq);
  // standalone scale+gelu (measured twice: fusing this regresses — keep separate)
  gelu_kernel<<<(M_TOT * N2T) / (256 * 8), 256, 0, stream>>>(S, rowsq);
  // GEMM2: out = W @ VbT^T [8192,1024], K=2048
  gemm2p_kernel<128, N2T, OUT_F, 0><<<256, 512, 0, stream>>>(S, VbT, d_out, nullptr);
}

// Round 10
// 137.694 us; speedup vs baseline: 1.0174x; 1.0174x over previous
//
#include <hip/hip_runtime.h>

#define IN_F 1024
#define OUT_F 1024
#define NT 1024
#define RANK 32
#define M_TOT 8192   // 4*2048 query rows
#define N2T 2048     // 2*NT combined tokens

typedef __attribute__((ext_vector_type(8))) short short8;
typedef __attribute__((ext_vector_type(4))) float f32x4;
typedef __attribute__((ext_vector_type(8))) unsigned short ushort8;

__device__ __forceinline__ float geluf(float x) {
  return 0.5f * x * (1.0f + erff(x * 0.7071067811865476f));
}
__device__ __forceinline__ unsigned short f2bf(float f) {
  unsigned x = __float_as_uint(f);
  return (unsigned short)((x + 0x7fffu + ((x >> 16) & 1u)) >> 16);
}
__device__ __forceinline__ float bf2f(unsigned short u) {
  return __uint_as_float(((unsigned)u) << 16);
}

// ---- prep kernels ----------------------------------------------------------

// tmp = T @ D  ([1024][32]); 4 rows per block, transposed LDS staging; zeroes rowsq
__global__ __launch_bounds__(256) void down_proj_kernel(
    const float* __restrict__ kt, const float* __restrict__ kd,
    const float* __restrict__ vt, const float* __restrict__ vd,
    float* __restrict__ tmpK, float* __restrict__ tmpV,
    float* __restrict__ rowsq) {
  __shared__ float rowbufT[IN_F][4];   // [k][row] 16 KB
  __shared__ float part[8][32][4];     // [kchunk][c][row] 4 KB
  const int tid = threadIdx.x;
  if (blockIdx.x < 32) rowsq[blockIdx.x * 256 + tid] = 0.f;
  const int mat = blockIdx.x >> 8;          // 256 blocks per matrix
  const int r0 = (blockIdx.x & 255) * 4;
  const float* T = mat ? vt : kt;
  const float* D = mat ? vd : kd;
  float* OUT = mat ? tmpV : tmpK;
  {
    const int rr = tid >> 6;
    const int lane = tid & 63;
#pragma unroll
    for (int i = 0; i < 4; ++i) {
      int col = lane * 4 + i * 256;
      f32x4 v = *(const f32x4*)(T + (size_t)(r0 + rr) * IN_F + col);
#pragma unroll
      for (int j = 0; j < 4; ++j) rowbufT[col + j][rr] = v[j];
    }
  }
  __syncthreads();
  const int c = tid & 31;
  const int kc = tid >> 5;  // 8 chunks of 128 k
  float s0 = 0.f, s1 = 0.f, s2 = 0.f, s3 = 0.f;
#pragma unroll 4
  for (int k = kc * 128; k < kc * 128 + 128; ++k) {
    float d = D[k * RANK + c];
    f32x4 r = *(const f32x4*)(&rowbufT[k][0]);
    s0 += r[0] * d; s1 += r[1] * d; s2 += r[2] * d; s3 += r[3] * d;
  }
  *(f32x4*)(&part[kc][c][0]) = (f32x4){s0, s1, s2, s3};
  __syncthreads();
  if (tid < 128) {
    const int rr = tid >> 5;
    const int cc = tid & 31;
    float a = 0.f;
#pragma unroll
    for (int i = 0; i < 8; ++i) a += part[i][cc][rr];
    OUT[(size_t)(r0 + rr) * RANK + cc] = a;
  }
}

// One merged prep kernel (casts now 16 elems/thread):
//   [0,2048)    xcast x -> xb
//   [2048,2304) cast key_tokens -> Kb[0:NT]
//   [2304,2816) upK: Kb[NT+t][d] = bf16(gelu(tmpK @ key_up))
//   [2816,3072) vcopy: VbT[e][t<NT] = transpose(value_tokens)
//   [3072,3584) upV: VbT[e][NT+t] = bf16(gelu(tmpV @ value_up))
__global__ __launch_bounds__(256) void prep_all_kernel(
    const float* __restrict__ x, const float* __restrict__ key_tokens,
    const float* __restrict__ value_tokens, const float* __restrict__ key_up,
    const float* __restrict__ value_up, const float* __restrict__ tmpK,
    const float* __restrict__ tmpV, unsigned short* __restrict__ xb,
    unsigned short* __restrict__ Kb, unsigned short* __restrict__ VbT) {
  __shared__ float smem[64 * 65 + 32 * 64];
  const int tid = threadIdx.x;
  const int bid = blockIdx.x;
  if (bid < 2304) {
    const float* src = (bid < 2048) ? x : key_tokens;
    unsigned short* dst = (bid < 2048) ? xb : Kb;
    int b = (bid < 2048) ? bid : (bid - 2048);
    int base = (b * 256 + tid) * 16;
    f32x4 a0 = *(const f32x4*)(src + base);
    f32x4 a1 = *(const f32x4*)(src + base + 4);
    f32x4 a2 = *(const f32x4*)(src + base + 8);
    f32x4 a3 = *(const f32x4*)(src + base + 12);
    ushort8 o0, o1;
    o0[0] = f2bf(a0[0]); o0[1] = f2bf(a0[1]); o0[2] = f2bf(a0[2]); o0[3] = f2bf(a0[3]);
    o0[4] = f2bf(a1[0]); o0[5] = f2bf(a1[1]); o0[6] = f2bf(a1[2]); o0[7] = f2bf(a1[3]);
    o1[0] = f2bf(a2[0]); o1[1] = f2bf(a2[1]); o1[2] = f2bf(a2[2]); o1[3] = f2bf(a2[3]);
    o1[4] = f2bf(a3[0]); o1[5] = f2bf(a3[1]); o1[6] = f2bf(a3[2]); o1[7] = f2bf(a3[3]);
    *(ushort8*)(dst + base) = o0;
    *(ushort8*)(dst + base + 8) = o1;
    return;
  }
  if (bid < 2816) {
    const int b = bid - 2304;
    float* ldsT = smem;               // [32][33]
    float* ldsU = smem + 64 * 65;     // [32][64]
    const int t0 = (b >> 4) * 32;
    const int d0 = (b & 15) * 64;
    {
      int row = tid >> 3, col = (tid & 7) * 4;
      f32x4 v = *(const f32x4*)(tmpK + (size_t)(t0 + row) * RANK + col);
#pragma unroll
      for (int j = 0; j < 4; ++j) ldsT[row * 33 + col + j] = v[j];
    }
#pragma unroll
    for (int s = 0; s < 2; ++s) {
      int idx = s * 1024 + tid * 4;
      int r = idx >> 6, cc = idx & 63;
      *(f32x4*)(ldsU + idx) = *(const f32x4*)(key_up + (size_t)r * IN_F + d0 + cc);
    }
    __syncthreads();
    const int lane = tid & 63;
    const int w = tid >> 6;
    float acc[8];
#pragma unroll
    for (int i = 0; i < 8; ++i) acc[i] = 0.f;
#pragma unroll
    for (int r = 0; r < RANK; ++r) {
      float wv = ldsU[r * 64 + lane];
#pragma unroll
      for (int i = 0; i < 8; ++i) acc[i] += ldsT[(w * 8 + i) * 33 + r] * wv;
    }
#pragma unroll
    for (int i = 0; i < 8; ++i)
      Kb[(size_t)(NT + t0 + w * 8 + i) * IN_F + d0 + lane] = f2bf(geluf(acc[i]));
    return;
  }
  if (bid < 3072) {
    const int b = bid - 2816;
    float (*tile)[65] = (float (*)[65])smem;
    int t0 = (b & 15) * 64, e0 = (b >> 4) * 64;
#pragma unroll 1
    for (int it = 0; it < 16; ++it) {
      int tt = it * 4 + (tid >> 6);
      int ee = tid & 63;
      tile[tt][ee] = value_tokens[(size_t)(t0 + tt) * OUT_F + e0 + ee];
    }
    __syncthreads();
#pragma unroll 1
    for (int it = 0; it < 16; ++it) {
      int ee = it * 4 + (tid >> 6);
      int tt = tid & 63;
      VbT[(size_t)(e0 + ee) * N2T + t0 + tt] = f2bf(tile[tt][ee]);
    }
    return;
  }
  {
    const int b = bid - 3072;
    float* ldsT = smem;               // [64][33]
    float* ldsU = smem + 64 * 65;     // [32][32]
    const int t0 = (b >> 5) * 64;
    const int e0 = (b & 31) * 32;
#pragma unroll
    for (int s = 0; s < 2; ++s) {
      int idx = s * 1024 + tid * 4;
      int row = idx >> 5, col = idx & 31;
      f32x4 v = *(const f32x4*)(tmpV + (size_t)(t0 + row) * RANK + col);
#pragma unroll
      for (int j = 0; j < 4; ++j) ldsT[row * 33 + col + j] = v[j];
    }
    {
      int r = tid >> 3, col = (tid & 7) * 4;
      *(f32x4*)(ldsU + r * 32 + col) = *(const f32x4*)(value_up + (size_t)r * OUT_F + e0 + col);
    }
    __syncthreads();
    const int lane = tid & 63;
    const int w = tid >> 6;
    float acc[8];
#pragma unroll
    for (int i = 0; i < 8; ++i) acc[i] = 0.f;
#pragma unroll
    for (int r = 0; r < RANK; ++r) {
      float uv = ldsT[lane * 33 + r];
#pragma unroll
      for (int i = 0; i < 8; ++i) acc[i] += uv * ldsU[r * 32 + w * 8 + i];
    }
#pragma unroll
    for (int i = 0; i < 8; ++i)
      VbT[(size_t)(e0 + w * 8 + i) * N2T + NT + t0 + lane] = f2bf(geluf(acc[i]));
  }
}

// standalone scale+gelu pass, 16 elems/thread: W = bf16(gelu(S*scale)) in place
__global__ void gelu_kernel(unsigned short* __restrict__ S, const float* __restrict__ rowsq) {
  int base = (blockIdx.x * blockDim.x + threadIdx.x) * 16;
  int row = base >> 11;   // 2048 per row; 16 | 2048 so no straddle
  float scale = sqrtf(2048.0f / rowsq[row]);
  ushort8 v0 = *(const ushort8*)(S + base);
  ushort8 v1 = *(const ushort8*)(S + base + 8);
  ushort8 o0, o1;
#pragma unroll
  for (int i = 0; i < 8; ++i) o0[i] = f2bf(geluf(bf2f(v0[i]) * scale));
#pragma unroll
  for (int i = 0; i < 8; ++i) o1[i] = f2bf(geluf(bf2f(v1[i]) * scale));
  *(ushort8*)(S + base) = o0;
  *(ushort8*)(S + base + 8) = o1;
}

// ---- 2-phase GEMM (R4-verified): C[M,N] = A[M,K]*B[N,K]^T, BM=256, BK=64 ---
// Phase A reads A0,B0,B1 -> 32 MFMA; phase B reads A1 -> 32 MFMA.
// Stage slots (>=1 barrier after target region's last read):
//   phA: A1(t+1) -> other buf; phB: A0,B0,B1(t+2) -> current buf.
// Boundary vmcnt(2+2*LB): drains through t.phA's A1(t+1) -> t+1 fully staged.
#define BARRB __builtin_amdgcn_s_barrier()

template <int BN, int KDIM, int NDIM, int DO_SIM>
__global__ __launch_bounds__(512, 2) void gemm2p_kernel(
    const unsigned short* __restrict__ A, const unsigned short* __restrict__ Bm,
    void* __restrict__ Cout, float* __restrict__ rowsq) {
  constexpr int NFRAG = BN / 64;
  constexpr int NH = NFRAG / 2;
  constexpr int LB = BN / 128;
  constexpr int ABUFE = 16384;
  constexpr int BBUFE = BN * 64;
  constexpr int nTN = NDIM / BN;
  constexpr int nkt = KDIM / 64;
  __shared__ unsigned short lds[2 * ABUFE + 2 * BBUFE];

  const int tid = threadIdx.x;
  const int l = tid & 63;
  const int wid = tid >> 6;
  const int wr = wid >> 2;
  const int wc = wid & 3;

  const int nwg = gridDim.x;
  const int cpx = nwg >> 3;
  const int wg = (blockIdx.x & 7) * cpx + (blockIdx.x >> 3);
  const int bx = wg % nTN;
  const int by = wg / nTN;
  const int rowBase = by * 256;
  const int colBase = bx * BN;

  const unsigned short* aSrc[2]; int aLds[2];
#pragma unroll
  for (int j = 0; j < 2; ++j) {
    int slot = j * 512 + tid;
    int rin = slot >> 3;
    int cs = (slot & 7) ^ (rin & 7);
    aSrc[j] = A + (size_t)(rowBase + rin) * KDIM + cs * 8;
    aLds[j] = slot * 8;
  }
  const unsigned short* bSrc[LB]; int bLds[LB];
#pragma unroll
  for (int j = 0; j < LB; ++j) {
    int slot = j * 512 + tid;
    int rin = slot >> 3;
    int cs = (slot & 7) ^ (rin & 7);
    bSrc[j] = Bm + (size_t)(colBase + rin) * KDIM + cs * 8;
    bLds[j] = slot * 8;
  }

#define STAGE_A(u, b, kt) { _Pragma("unroll") for (int j = 0; j < 2; ++j) \
    __builtin_amdgcn_global_load_lds( \
      (const __attribute__((address_space(1))) void*)(aSrc[j] + (size_t)(u) * 128 * KDIM + (kt) * 64), \
      (__attribute__((address_space(3))) void*)(lds + (b) * ABUFE + (u) * 8192 + aLds[j]), 16, 0, 0); }
#define STAGE_B(u, b, kt) { _Pragma("unroll") for (int j = 0; j < LB; ++j) \
    __builtin_amdgcn_global_load_lds( \
      (const __attribute__((address_space(1))) void*)(bSrc[j] + (size_t)(u) * (BN / 2) * KDIM + (kt) * 64), \
      (__attribute__((address_space(3))) void*)(lds + 2 * ABUFE + (b) * BBUFE + (u) * (BBUFE / 2) + bLds[j]), 16, 0, 0); }

  const int kb0 = (l >> 4) * 16;
  const int sw = (l & 7) << 4;
  const int lr = l & 15;

  f32x4 acc[8][NFRAG];
#pragma unroll
  for (int m = 0; m < 8; ++m)
#pragma unroll
    for (int n = 0; n < NFRAG; ++n) acc[m][n] = (f32x4){0.f, 0.f, 0.f, 0.f};

  short8 a[4][2], b0[NH][2], b1[NH][2];

#define LDA(mh, bb_) { _Pragma("unroll") for (int i = 0; i < 4; ++i) { \
    int row = ((mh) * 4 + i) * 32 + wr * 16 + lr; \
    const char* pp = (const char*)lds + (bb_) * 32768 + row * 128; \
    a[i][0] = *(const short8*)(pp + ((0 + kb0) ^ sw)); \
    a[i][1] = *(const short8*)(pp + ((64 + kb0) ^ sw)); } }
#define LDB(dst, nh, bb_) { _Pragma("unroll") for (int i = 0; i < NH; ++i) { \
    int row = ((nh) * NH + i) * 64 + wc * 16 + lr; \
    const char* pp = (const char*)lds + 2 * ABUFE * 2 + (bb_) * BBUFE * 2 + row * 128; \
    dst[i][0] = *(const short8*)(pp + ((0 + kb0) ^ sw)); \
    dst[i][1] = *(const short8*)(pp + ((64 + kb0) ^ sw)); } }
#define DO_MFMA(mh, nh, bb) { _Pragma("unroll") for (int kk = 0; kk < 2; ++kk) \
    _Pragma("unroll") for (int i = 0; i < 4; ++i) \
    _Pragma("unroll") for (int nn = 0; nn < NH; ++nn) \
      acc[(mh) * 4 + i][(nh) * NH + nn] = __builtin_amdgcn_mfma_f32_16x16x32_bf16( \
          a[i][kk], bb[nn][kk], acc[(mh) * 4 + i][(nh) * NH + nn], 0, 0, 0); }

  STAGE_A(0, 0, 0); STAGE_A(1, 0, 0); STAGE_B(0, 0, 0); STAGE_B(1, 0, 0);
  STAGE_A(0, 1, 1); STAGE_B(0, 1, 1); STAGE_B(1, 1, 1);
  if constexpr (LB == 2) { asm volatile("s_waitcnt vmcnt(6)" ::: "memory"); }
  else                   { asm volatile("s_waitcnt vmcnt(4)" ::: "memory"); }
  BARRB;

  for (int t = 0; t < nkt; ++t) {
    const int buf = t & 1;
    LDA(0, buf); LDB(b0, 0, buf); LDB(b1, 1, buf);
    if (t + 1 < nkt) STAGE_A(1, buf ^ 1, t + 1);
    BARRB;
    __builtin_amdgcn_s_setprio(1);
    DO_MFMA(0, 0, b0); DO_MFMA(0, 1, b1);
    __builtin_amdgcn_s_setprio(0);
    BARRB;
    LDA(1, buf);
    if (t + 2 < nkt) { STAGE_A(0, buf, t + 2); STAGE_B(0, buf, t + 2); STAGE_B(1, buf, t + 2); }
    BARRB;
    __builtin_amdgcn_s_setprio(1);
    DO_MFMA(1, 1, b1); DO_MFMA(1, 0, b0);
    __builtin_amdgcn_s_setprio(0);
    if constexpr (LB == 2) { asm volatile("s_waitcnt vmcnt(6)" ::: "memory"); }
    else                   { asm volatile("s_waitcnt vmcnt(4)" ::: "memory"); }
    BARRB;
  }

  // epilogue: C/D layout col=lane&15, row=(lane>>4)*4+reg
  const int cq = l >> 4;
  const int cc = l & 15;
  if constexpr (DO_SIM) {
    unsigned short* Sb = (unsigned short*)Cout;
#pragma unroll
    for (int m = 0; m < 8; ++m) {
#pragma unroll
      for (int j = 0; j < 4; ++j) {
        int gr = rowBase + m * 32 + wr * 16 + cq * 4 + j;
        float ss = 0.f;
#pragma unroll
        for (int n = 0; n < NFRAG; ++n) {
          float v = acc[m][n][j];
          ss += v * v;
          Sb[(size_t)gr * NDIM + colBase + n * 64 + wc * 16 + cc] = f2bf(v);
        }
        ss += __shfl_xor(ss, 1, 64);
        ss += __shfl_xor(ss, 2, 64);
        ss += __shfl_xor(ss, 4, 64);
        ss += __shfl_xor(ss, 8, 64);
        if (cc == 0) atomicAdd(&rowsq[gr], ss);
      }
    }
  } else {
    float* Co = (float*)Cout;
#pragma unroll
    for (int m = 0; m < 8; ++m) {
#pragma unroll
      for (int j = 0; j < 4; ++j) {
        int gr = rowBase + m * 32 + wr * 16 + cq * 4 + j;
#pragma unroll
        for (int n = 0; n < NFRAG; ++n)
          Co[(size_t)gr * NDIM + colBase + n * 64 + wc * 16 + cc] = acc[m][n][j];
      }
    }
  }
#undef STAGE_A
#undef STAGE_B
#undef LDA
#undef LDB
#undef DO_MFMA
}

// ---- launch ----------------------------------------------------------------

extern "C" void kernel_launch(void* const* d_in, const int* in_sizes, int n_in,
                              void* d_out, int out_size, void* d_ws, size_t ws_size,
                              hipStream_t stream) {
  (void)in_sizes; (void)n_in; (void)out_size; (void)ws_size;
  const float* x            = (const float*)d_in[0];
  const float* key_tokens   = (const float*)d_in[1];
  const float* value_tokens = (const float*)d_in[2];
  const float* key_down     = (const float*)d_in[3];
  const float* key_up       = (const float*)d_in[4];
  const float* value_down   = (const float*)d_in[5];
  const float* value_up     = (const float*)d_in[6];

  char* ws = (char*)d_ws;
  unsigned short* xb  = (unsigned short*)(ws);              // 16 MB  [8192][1024]
  unsigned short* Kb  = (unsigned short*)(ws + 16777216);   // 4 MB   [2048][1024]
  unsigned short* VbT = (unsigned short*)(ws + 20971520);   // 4 MB   [1024][2048]
  unsigned short* S   = (unsigned short*)(ws + 25165824);   // 32 MB  [8192][2048]
  float* tmpK  = (float*)(ws + 58720256);                   // 128 KB
  float* tmpV  = (float*)(ws + 58851328);                   // 128 KB
  float* rowsq = (float*)(ws + 58982400);                   // 32 KB

  down_proj_kernel<<<512, 256, 0, stream>>>(key_tokens, key_down, value_tokens, value_down,
                                            tmpK, tmpV, rowsq);
  prep_all_kernel<<<3584, 256, 0, stream>>>(x, key_tokens, value_tokens, key_up, value_up,
                                            tmpK, tmpV, xb, Kb, VbT);
  // GEMM1: S = xb @ Kb^T  [8192,2048], K=1024 (+ rowsq)
  gemm2p_kernel<256, IN_F, N2T, 1><<<256, 512, 0, stream>>>(xb, Kb, (void*)S, rowsq);
  // standalone scale+gelu (measured twice: fusing this regresses — keep separate)
  gelu_kernel<<<(M_TOT * N2T) / (256 * 16), 256, 0, stream>>>(S, rowsq);
  // GEMM2: out = W @ VbT^T [8192,1024], K=2048
  gemm2p_kernel<128, N2T, OUT_F, 0><<<256, 512, 0, stream>>>(S, VbT, d_out, nullptr);
}

// Round 12
// 137.588 us; speedup vs baseline: 1.0182x; 1.0008x over previous
//
#include <hip/hip_runtime.h>

#define IN_F 1024
#define OUT_F 1024
#define NT 1024
#define RANK 32
#define M_TOT 8192   // 4*2048 query rows
#define N2T 2048     // 2*NT combined tokens

typedef __attribute__((ext_vector_type(8))) short short8;
typedef __attribute__((ext_vector_type(4))) float f32x4;
typedef __attribute__((ext_vector_type(8))) unsigned short ushort8;

__device__ __forceinline__ float geluf(float x) {
  return 0.5f * x * (1.0f + erff(x * 0.7071067811865476f));
}
__device__ __forceinline__ unsigned short f2bf(float f) {
  unsigned x = __float_as_uint(f);
  return (unsigned short)((x + 0x7fffu + ((x >> 16) & 1u)) >> 16);
}
__device__ __forceinline__ float bf2f(unsigned short u) {
  return __uint_as_float(((unsigned)u) << 16);
}

// ---- prep kernels ----------------------------------------------------------

// tmp = T @ D  ([1024][32]); 4 rows per block, transposed LDS staging; zeroes rowsq
__global__ __launch_bounds__(256) void down_proj_kernel(
    const float* __restrict__ kt, const float* __restrict__ kd,
    const float* __restrict__ vt, const float* __restrict__ vd,
    float* __restrict__ tmpK, float* __restrict__ tmpV,
    float* __restrict__ rowsq) {
  __shared__ float rowbufT[IN_F][4];   // [k][row] 16 KB
  __shared__ float part[8][32][4];     // [kchunk][c][row] 4 KB
  const int tid = threadIdx.x;
  if (blockIdx.x < 32) rowsq[blockIdx.x * 256 + tid] = 0.f;
  const int mat = blockIdx.x >> 8;          // 256 blocks per matrix
  const int r0 = (blockIdx.x & 255) * 4;
  const float* T = mat ? vt : kt;
  const float* D = mat ? vd : kd;
  float* OUT = mat ? tmpV : tmpK;
  {
    const int rr = tid >> 6;
    const int lane = tid & 63;
#pragma unroll
    for (int i = 0; i < 4; ++i) {
      int col = lane * 4 + i * 256;
      f32x4 v = *(const f32x4*)(T + (size_t)(r0 + rr) * IN_F + col);
#pragma unroll
      for (int j = 0; j < 4; ++j) rowbufT[col + j][rr] = v[j];
    }
  }
  __syncthreads();
  const int c = tid & 31;
  const int kc = tid >> 5;  // 8 chunks of 128 k
  float s0 = 0.f, s1 = 0.f, s2 = 0.f, s3 = 0.f;
#pragma unroll 4
  for (int k = kc * 128; k < kc * 128 + 128; ++k) {
    float d = D[k * RANK + c];
    f32x4 r = *(const f32x4*)(&rowbufT[k][0]);
    s0 += r[0] * d; s1 += r[1] * d; s2 += r[2] * d; s3 += r[3] * d;
  }
  *(f32x4*)(&part[kc][c][0]) = (f32x4){s0, s1, s2, s3};
  __syncthreads();
  if (tid < 128) {
    const int rr = tid >> 5;
    const int cc = tid & 31;
    float a = 0.f;
#pragma unroll
    for (int i = 0; i < 8; ++i) a += part[i][cc][rr];
    OUT[(size_t)(r0 + rr) * RANK + cc] = a;
  }
}

// One merged prep kernel (casts 16 elems/thread):
//   [0,2048)    xcast x -> xb
//   [2048,2304) cast key_tokens -> Kb[0:NT]
//   [2304,2816) upK: Kb[NT+t][d] = bf16(gelu(tmpK @ key_up))
//   [2816,3072) vcopy: VbT[e][t<NT] = transpose(value_tokens)
//   [3072,3584) upV: VbT[e][NT+t] = bf16(gelu(tmpV @ value_up))
__global__ __launch_bounds__(256) void prep_all_kernel(
    const float* __restrict__ x, const float* __restrict__ key_tokens,
    const float* __restrict__ value_tokens, const float* __restrict__ key_up,
    const float* __restrict__ value_up, const float* __restrict__ tmpK,
    const float* __restrict__ tmpV, unsigned short* __restrict__ xb,
    unsigned short* __restrict__ Kb, unsigned short* __restrict__ VbT) {
  __shared__ float smem[64 * 65 + 32 * 64];
  const int tid = threadIdx.x;
  const int bid = blockIdx.x;
  if (bid < 2304) {
    const float* src = (bid < 2048) ? x : key_tokens;
    unsigned short* dst = (bid < 2048) ? xb : Kb;
    int b = (bid < 2048) ? bid : (bid - 2048);
    int base = (b * 256 + tid) * 16;
    f32x4 a0 = *(const f32x4*)(src + base);
    f32x4 a1 = *(const f32x4*)(src + base + 4);
    f32x4 a2 = *(const f32x4*)(src + base + 8);
    f32x4 a3 = *(const f32x4*)(src + base + 12);
    ushort8 o0, o1;
    o0[0] = f2bf(a0[0]); o0[1] = f2bf(a0[1]); o0[2] = f2bf(a0[2]); o0[3] = f2bf(a0[3]);
    o0[4] = f2bf(a1[0]); o0[5] = f2bf(a1[1]); o0[6] = f2bf(a1[2]); o0[7] = f2bf(a1[3]);
    o1[0] = f2bf(a2[0]); o1[1] = f2bf(a2[1]); o1[2] = f2bf(a2[2]); o1[3] = f2bf(a2[3]);
    o1[4] = f2bf(a3[0]); o1[5] = f2bf(a3[1]); o1[6] = f2bf(a3[2]); o1[7] = f2bf(a3[3]);
    *(ushort8*)(dst + base) = o0;
    *(ushort8*)(dst + base + 8) = o1;
    return;
  }
  if (bid < 2816) {
    const int b = bid - 2304;
    float* ldsT = smem;               // [32][33]
    float* ldsU = smem + 64 * 65;     // [32][64]
    const int t0 = (b >> 4) * 32;
    const int d0 = (b & 15) * 64;
    {
      int row = tid >> 3, col = (tid & 7) * 4;
      f32x4 v = *(const f32x4*)(tmpK + (size_t)(t0 + row) * RANK + col);
#pragma unroll
      for (int j = 0; j < 4; ++j) ldsT[row * 33 + col + j] = v[j];
    }
#pragma unroll
    for (int s = 0; s < 2; ++s) {
      int idx = s * 1024 + tid * 4;
      int r = idx >> 6, cc = idx & 63;
      *(f32x4*)(ldsU + idx) = *(const f32x4*)(key_up + (size_t)r * IN_F + d0 + cc);
    }
    __syncthreads();
    const int lane = tid & 63;
    const int w = tid >> 6;
    float acc[8];
#pragma unroll
    for (int i = 0; i < 8; ++i) acc[i] = 0.f;
#pragma unroll
    for (int r = 0; r < RANK; ++r) {
      float wv = ldsU[r * 64 + lane];
#pragma unroll
      for (int i = 0; i < 8; ++i) acc[i] += ldsT[(w * 8 + i) * 33 + r] * wv;
    }
#pragma unroll
    for (int i = 0; i < 8; ++i)
      Kb[(size_t)(NT + t0 + w * 8 + i) * IN_F + d0 + lane] = f2bf(geluf(acc[i]));
    return;
  }
  if (bid < 3072) {
    const int b = bid - 2816;
    float (*tile)[65] = (float (*)[65])smem;
    int t0 = (b & 15) * 64, e0 = (b >> 4) * 64;
#pragma unroll 1
    for (int it = 0; it < 16; ++it) {
      int tt = it * 4 + (tid >> 6);
      int ee = tid & 63;
      tile[tt][ee] = value_tokens[(size_t)(t0 + tt) * OUT_F + e0 + ee];
    }
    __syncthreads();
#pragma unroll 1
    for (int it = 0; it < 16; ++it) {
      int ee = it * 4 + (tid >> 6);
      int tt = tid & 63;
      VbT[(size_t)(e0 + ee) * N2T + t0 + tt] = f2bf(tile[tt][ee]);
    }
    return;
  }
  {
    const int b = bid - 3072;
    float* ldsT = smem;               // [64][33]
    float* ldsU = smem + 64 * 65;     // [32][32]
    const int t0 = (b >> 5) * 64;
    const int e0 = (b & 31) * 32;
#pragma unroll
    for (int s = 0; s < 2; ++s) {
      int idx = s * 1024 + tid * 4;
      int row = idx >> 5, col = idx & 31;
      f32x4 v = *(const f32x4*)(tmpV + (size_t)(t0 + row) * RANK + col);
#pragma unroll
      for (int j = 0; j < 4; ++j) ldsT[row * 33 + col + j] = v[j];
    }
    {
      int r = tid >> 3, col = (tid & 7) * 4;
      *(f32x4*)(ldsU + r * 32 + col) = *(const f32x4*)(value_up + (size_t)r * OUT_F + e0 + col);
    }
    __syncthreads();
    const int lane = tid & 63;
    const int w = tid >> 6;
    float acc[8];
#pragma unroll
    for (int i = 0; i < 8; ++i) acc[i] = 0.f;
#pragma unroll
    for (int r = 0; r < RANK; ++r) {
      float uv = ldsT[lane * 33 + r];
#pragma unroll
      for (int i = 0; i < 8; ++i) acc[i] += uv * ldsU[r * 32 + w * 8 + i];
    }
#pragma unroll
    for (int i = 0; i < 8; ++i)
      VbT[(size_t)(e0 + w * 8 + i) * N2T + NT + t0 + lane] = f2bf(geluf(acc[i]));
  }
}

// standalone scale+gelu pass, 16 elems/thread: W = bf16(gelu(S*scale)) in place
__global__ void gelu_kernel(unsigned short* __restrict__ S, const float* __restrict__ rowsq) {
  int base = (blockIdx.x * blockDim.x + threadIdx.x) * 16;
  int row = base >> 11;   // 2048 per row; 16 | 2048 so no straddle
  float scale = sqrtf(2048.0f / rowsq[row]);
  ushort8 v0 = *(const ushort8*)(S + base);
  ushort8 v1 = *(const ushort8*)(S + base + 8);
  ushort8 o0, o1;
#pragma unroll
  for (int i = 0; i < 8; ++i) o0[i] = f2bf(geluf(bf2f(v0[i]) * scale));
#pragma unroll
  for (int i = 0; i < 8; ++i) o1[i] = f2bf(geluf(bf2f(v1[i]) * scale));
  *(ushort8*)(S + base) = o0;
  *(ushort8*)(S + base + 8) = o1;
}

// ---- 2-phase GEMM (R4-verified): C[M,N] = A[M,K]*B[N,K]^T, BM=256, BK=64 ---
// Phase A reads A0,B0,B1 -> 32 MFMA; phase B reads A1 -> 32 MFMA.
// Stage slots (>=1 barrier after target region's last read):
//   phA: A1(t+1) -> other buf; phB: A0,B0,B1(t+2) -> current buf.
// Boundary vmcnt(2+2*LB): drains through t.phA's A1(t+1) -> t+1 fully staged.
#define BARRB __builtin_amdgcn_s_barrier()

template <int BN, int KDIM, int NDIM, int DO_SIM>
__global__ __launch_bounds__(512, 2) void gemm2p_kernel(
    const unsigned short* __restrict__ A, const unsigned short* __restrict__ Bm,
    void* __restrict__ Cout, float* __restrict__ rowsq) {
  constexpr int NFRAG = BN / 64;
  constexpr int NH = NFRAG / 2;
  constexpr int LB = BN / 128;
  constexpr int ABUFE = 16384;
  constexpr int BBUFE = BN * 64;
  constexpr int nTN = NDIM / BN;
  constexpr int nkt = KDIM / 64;
  __shared__ unsigned short lds[2 * ABUFE + 2 * BBUFE];

  const int tid = threadIdx.x;
  const int l = tid & 63;
  const int wid = tid >> 6;
  const int wr = wid >> 2;
  const int wc = wid & 3;

  const int nwg = gridDim.x;
  const int cpx = nwg >> 3;
  const int wg = (blockIdx.x & 7) * cpx + (blockIdx.x >> 3);
  const int bx = wg % nTN;
  const int by = wg / nTN;
  const int rowBase = by * 256;
  const int colBase = bx * BN;

  const unsigned short* aSrc[2]; int aLds[2];
#pragma unroll
  for (int j = 0; j < 2; ++j) {
    int slot = j * 512 + tid;
    int rin = slot >> 3;
    int cs = (slot & 7) ^ (rin & 7);
    aSrc[j] = A + (size_t)(rowBase + rin) * KDIM + cs * 8;
    aLds[j] = slot * 8;
  }
  const unsigned short* bSrc[LB]; int bLds[LB];
#pragma unroll
  for (int j = 0; j < LB; ++j) {
    int slot = j * 512 + tid;
    int rin = slot >> 3;
    int cs = (slot & 7) ^ (rin & 7);
    bSrc[j] = Bm + (size_t)(colBase + rin) * KDIM + cs * 8;
    bLds[j] = slot * 8;
  }

#define STAGE_A(u, b, kt) { _Pragma("unroll") for (int j = 0; j < 2; ++j) \
    __builtin_amdgcn_global_load_lds( \
      (const __attribute__((address_space(1))) void*)(aSrc[j] + (size_t)(u) * 128 * KDIM + (kt) * 64), \
      (__attribute__((address_space(3))) void*)(lds + (b) * ABUFE + (u) * 8192 + aLds[j]), 16, 0, 0); }
#define STAGE_B(u, b, kt) { _Pragma("unroll") for (int j = 0; j < LB; ++j) \
    __builtin_amdgcn_global_load_lds( \
      (const __attribute__((address_space(1))) void*)(bSrc[j] + (size_t)(u) * (BN / 2) * KDIM + (kt) * 64), \
      (__attribute__((address_space(3))) void*)(lds + 2 * ABUFE + (b) * BBUFE + (u) * (BBUFE / 2) + bLds[j]), 16, 0, 0); }

  const int kb0 = (l >> 4) * 16;
  const int sw = (l & 7) << 4;
  const int lr = l & 15;

  f32x4 acc[8][NFRAG];
#pragma unroll
  for (int m = 0; m < 8; ++m)
#pragma unroll
    for (int n = 0; n < NFRAG; ++n) acc[m][n] = (f32x4){0.f, 0.f, 0.f, 0.f};

  short8 a[4][2], b0[NH][2], b1[NH][2];

#define LDA(mh, bb_) { _Pragma("unroll") for (int i = 0; i < 4; ++i) { \
    int row = ((mh) * 4 + i) * 32 + wr * 16 + lr; \
    const char* pp = (const char*)lds + (bb_) * 32768 + row * 128; \
    a[i][0] = *(const short8*)(pp + ((0 + kb0) ^ sw)); \
    a[i][1] = *(const short8*)(pp + ((64 + kb0) ^ sw)); } }
#define LDB(dst, nh, bb_) { _Pragma("unroll") for (int i = 0; i < NH; ++i) { \
    int row = ((nh) * NH + i) * 64 + wc * 16 + lr; \
    const char* pp = (const char*)lds + 2 * ABUFE * 2 + (bb_) * BBUFE * 2 + row * 128; \
    dst[i][0] = *(const short8*)(pp + ((0 + kb0) ^ sw)); \
    dst[i][1] = *(const short8*)(pp + ((64 + kb0) ^ sw)); } }
#define DO_MFMA(mh, nh, bb) { _Pragma("unroll") for (int kk = 0; kk < 2; ++kk) \
    _Pragma("unroll") for (int i = 0; i < 4; ++i) \
    _Pragma("unroll") for (int nn = 0; nn < NH; ++nn) \
      acc[(mh) * 4 + i][(nh) * NH + nn] = __builtin_amdgcn_mfma_f32_16x16x32_bf16( \
          a[i][kk], bb[nn][kk], acc[(mh) * 4 + i][(nh) * NH + nn], 0, 0, 0); }

  STAGE_A(0, 0, 0); STAGE_A(1, 0, 0); STAGE_B(0, 0, 0); STAGE_B(1, 0, 0);
  STAGE_A(0, 1, 1); STAGE_B(0, 1, 1); STAGE_B(1, 1, 1);
  if constexpr (LB == 2) { asm volatile("s_waitcnt vmcnt(6)" ::: "memory"); }
  else                   { asm volatile("s_waitcnt vmcnt(4)" ::: "memory"); }
  BARRB;

  for (int t = 0; t < nkt; ++t) {
    const int buf = t & 1;
    LDA(0, buf); LDB(b0, 0, buf); LDB(b1, 1, buf);
    if (t + 1 < nkt) STAGE_A(1, buf ^ 1, t + 1);
    BARRB;
    __builtin_amdgcn_s_setprio(1);
    DO_MFMA(0, 0, b0); DO_MFMA(0, 1, b1);
    __builtin_amdgcn_s_setprio(0);
    BARRB;
    LDA(1, buf);
    if (t + 2 < nkt) { STAGE_A(0, buf, t + 2); STAGE_B(0, buf, t + 2); STAGE_B(1, buf, t + 2); }
    BARRB;
    __builtin_amdgcn_s_setprio(1);
    DO_MFMA(1, 1, b1); DO_MFMA(1, 0, b0);
    __builtin_amdgcn_s_setprio(0);
    if constexpr (LB == 2) { asm volatile("s_waitcnt vmcnt(6)" ::: "memory"); }
    else                   { asm volatile("s_waitcnt vmcnt(4)" ::: "memory"); }
    BARRB;
  }

  // epilogue: C/D layout col=lane&15, row=(lane>>4)*4+reg
  const int cq = l >> 4;
  const int cc = l & 15;
  if constexpr (DO_SIM) {
    unsigned short* Sb = (unsigned short*)Cout;
#pragma unroll
    for (int m = 0; m < 8; ++m) {
#pragma unroll
      for (int j = 0; j < 4; ++j) {
        int gr = rowBase + m * 32 + wr * 16 + cq * 4 + j;
        float ss = 0.f;
#pragma unroll
        for (int n = 0; n < NFRAG; ++n) {
          float v = acc[m][n][j];
          ss += v * v;
          Sb[(size_t)gr * NDIM + colBase + n * 64 + wc * 16 + cc] = f2bf(v);
        }
        ss += __shfl_xor(ss, 1, 64);
        ss += __shfl_xor(ss, 2, 64);
        ss += __shfl_xor(ss, 4, 64);
        ss += __shfl_xor(ss, 8, 64);
        if (cc == 0) atomicAdd(&rowsq[gr], ss);
      }
    }
  } else {
    float* Co = (float*)Cout;
#pragma unroll
    for (int m = 0; m < 8; ++m) {
#pragma unroll
      for (int j = 0; j < 4; ++j) {
        int gr = rowBase + m * 32 + wr * 16 + cq * 4 + j;
#pragma unroll
        for (int n = 0; n < NFRAG; ++n)
          Co[(size_t)gr * NDIM + colBase + n * 64 + wc * 16 + cc] = acc[m][n][j];
      }
    }
  }
#undef STAGE_A
#undef STAGE_B
#undef LDA
#undef LDB
#undef DO_MFMA
}

// ---- launch ----------------------------------------------------------------

extern "C" void kernel_launch(void* const* d_in, const int* in_sizes, int n_in,
                              void* d_out, int out_size, void* d_ws, size_t ws_size,
                              hipStream_t stream) {
  (void)in_sizes; (void)n_in; (void)out_size; (void)ws_size;
  const float* x            = (const float*)d_in[0];
  const float* key_tokens   = (const float*)d_in[1];
  const float* value_tokens = (const float*)d_in[2];
  const float* key_down     = (const float*)d_in[3];
  const float* key_up       = (const float*)d_in[4];
  const float* value_down   = (const float*)d_in[5];
  const float* value_up     = (const float*)d_in[6];

  char* ws = (char*)d_ws;
  unsigned short* xb  = (unsigned short*)(ws);              // 16 MB  [8192][1024]
  unsigned short* Kb  = (unsigned short*)(ws + 16777216);   // 4 MB   [2048][1024]
  unsigned short* VbT = (unsigned short*)(ws + 20971520);   // 4 MB   [1024][2048]
  unsigned short* S   = (unsigned short*)(ws + 25165824);   // 32 MB  [8192][2048]
  float* tmpK  = (float*)(ws + 58720256);                   // 128 KB
  float* tmpV  = (float*)(ws + 58851328);                   // 128 KB
  float* rowsq = (float*)(ws + 58982400);                   // 32 KB

  down_proj_kernel<<<512, 256, 0, stream>>>(key_tokens, key_down, value_tokens, value_down,
                                            tmpK, tmpV, rowsq);
  prep_all_kernel<<<3584, 256, 0, stream>>>(x, key_tokens, value_tokens, key_up, value_up,
                                            tmpK, tmpV, xb, Kb, VbT);
  // GEMM1: S = xb @ Kb^T  [8192,2048], K=1024 (+ rowsq)
  gemm2p_kernel<256, IN_F, N2T, 1><<<256, 512, 0, stream>>>(xb, Kb, (void*)S, rowsq);
  // standalone scale+gelu (measured twice: fusing this regresses — keep separate)
  gelu_kernel<<<(M_TOT * N2T) / (256 * 16), 256, 0, stream>>>(S, rowsq);
  // GEMM2: out = W @ VbT^T [8192,1024], K=2048
  gemm2p_kernel<128, N2T, OUT_F, 0><<<256, 512, 0, stream>>>(S, VbT, d_out, nullptr);
}